// Round 3
// baseline (3124.188 us; speedup 1.0000x reference)
//
#include <hip/hip_runtime.h>
#include <hip/hip_bf16.h>
#include <cstdint>

typedef float f32x4 __attribute__((ext_vector_type(4)));
typedef short bf16x8 __attribute__((ext_vector_type(8)));

__device__ __forceinline__ unsigned short f32_to_bf16_rne(float f) {
  unsigned int u = __float_as_uint(f);
  return (unsigned short)((u + 0x7FFFu + ((u >> 16) & 1u)) >> 16);
}

#define GLOAD_LDS16(gptr, lptr)                                                             \
  __builtin_amdgcn_global_load_lds((const __attribute__((address_space(1))) unsigned int*)(gptr), \
                                   (__attribute__((address_space(3))) unsigned int*)(lptr), 16, 0, 0)

// ---------------- fused f32 -> bf16 for all 5 operands (8 elems / thread) ----------------
__global__ __launch_bounds__(256) void cvt_all(const float* __restrict__ wv,
                                               const float* __restrict__ q,
                                               const float* __restrict__ v,
                                               const float* __restrict__ wq,
                                               const float* __restrict__ wo,
                                               unsigned short* __restrict__ wvb,
                                               unsigned short* __restrict__ qb,
                                               unsigned short* __restrict__ vb,
                                               unsigned short* __restrict__ wqb,
                                               unsigned short* __restrict__ wob) {
  int i = blockIdx.x * 256 + threadIdx.x;  // chunk of 8 floats
  const float* src;
  unsigned short* dst;
  int off;
  if (i < 4194304)      { src = wv; dst = wvb; off = i; }
  else if (i < 4456448) { src = q;  dst = qb;  off = i - 4194304; }
  else if (i < 4718592) { src = v;  dst = vb;  off = i - 4456448; }
  else if (i < 4849664) { src = wq; dst = wqb; off = i - 4718592; }
  else                  { src = wo; dst = wob; off = i - 4849664; }
  const float4* s = (const float4*)src;
  float4 a = s[2 * off], b = s[2 * off + 1];
  uint4 o;
  o.x = (unsigned)f32_to_bf16_rne(a.x) | ((unsigned)f32_to_bf16_rne(a.y) << 16);
  o.y = (unsigned)f32_to_bf16_rne(a.z) | ((unsigned)f32_to_bf16_rne(a.w) << 16);
  o.z = (unsigned)f32_to_bf16_rne(b.x) | ((unsigned)f32_to_bf16_rne(b.y) << 16);
  o.w = (unsigned)f32_to_bf16_rne(b.z) | ((unsigned)f32_to_bf16_rne(b.w) << 16);
  ((uint4*)dst)[off] = o;
}

// ---------------- fuzzy membership + softmax over rules ----------------
__global__ __launch_bounds__(256) void fuzzy_softmax_k(const float* __restrict__ qf,
                                                       const float* __restrict__ rk,
                                                       const float* __restrict__ rw,
                                                       float* __restrict__ attn) {
  int p = blockIdx.x * 8 + (threadIdx.x >> 5);
  int r = threadIdx.x & 31;
  int m = p >> 4;
  int h = p & 15;
  const float* qrow = qf + (size_t)m * 1024 + h * 64;
  const float* krow = rk + (size_t)(h * 32 + r) * 64;
  const float* wrow = rw + (size_t)(h * 32 + r) * 64;
  float acc = 0.f;
#pragma unroll
  for (int d0 = 0; d0 < 64; d0 += 4) {
    float4 qv = *(const float4*)(qrow + d0);
    float4 kv = *(const float4*)(krow + d0);
    float4 wv = *(const float4*)(wrow + d0);
    float t;
    t = fabsf(qv.x - kv.x) / wv.x; acc += t * t;
    t = fabsf(qv.y - kv.y) / wv.y; acc += t * t;
    t = fabsf(qv.z - kv.z) / wv.z; acc += t * t;
    t = fabsf(qv.w - kv.w) / wv.w; acc += t * t;
  }
  float z = -0.5f * (acc * (1.0f / 64.0f));
  float mx = z;
#pragma unroll
  for (int mask = 16; mask >= 1; mask >>= 1) mx = fmaxf(mx, __shfl_xor(mx, mask));
  float e = __expf(z - mx);
  float s = e;
#pragma unroll
  for (int mask = 16; mask >= 1; mask >>= 1) s += __shfl_xor(s, mask);
  attn[(size_t)m * 512 + h * 32 + r] = e / s;
}

// ---------------- small bf16 GEMM (64x128 tile, 256 blocks): C = (A @ W^T + bias) * scale ----
__global__ __launch_bounds__(256) void gemm_bt64(const unsigned short* __restrict__ A,
                                                 const unsigned short* __restrict__ W,
                                                 const float* __restrict__ bias, float scale,
                                                 int M, int N, int K, float* __restrict__ Cf) {
  constexpr int BM = 64, BN = 128, BK = 32;
  __shared__ unsigned short As[2][BM * BK];
  __shared__ unsigned short Bs[2][BN * BK];
  const int tid = threadIdx.x;
  const int wid = tid >> 6;
  const int lane = tid & 63;
  const int l15 = lane & 15;
  const int l4 = lane >> 4;
  const int bm = blockIdx.y * BM;
  const int bn = blockIdx.x * BN;
  const int wc = wid * 32;  // wave col offset (4 waves x 32 cols)

  f32x4 acc[4][2];
#pragma unroll
  for (int i = 0; i < 4; ++i)
#pragma unroll
    for (int j = 0; j < 2; ++j) acc[i][j] = (f32x4){0.f, 0.f, 0.f, 0.f};

  const int nk = K / BK;
  auto stage = [&](int buf, int kt) {
    {  // A: 256 chunks of 16B
      int c = tid;
      int row = c >> 2, ch = c & 3;
      int sch = ch ^ ((row >> 1) & 3);
      GLOAD_LDS16(A + (size_t)(bm + row) * K + kt * BK + sch * 8, &As[buf][c * 8]);
    }
#pragma unroll
    for (int i = 0; i < 2; ++i) {  // B: 512 chunks
      int c = i * 256 + tid;
      int row = c >> 2, ch = c & 3;
      int sch = ch ^ ((row >> 1) & 3);
      GLOAD_LDS16(W + (size_t)(bn + row) * K + kt * BK + sch * 8, &Bs[buf][c * 8]);
    }
  };

  stage(0, 0);
  __syncthreads();

  for (int kt = 0; kt < nk; ++kt) {
    const int cur = kt & 1;
    if (kt + 1 < nk) stage(cur ^ 1, kt + 1);
    bf16x8 a[4], b[2];
#pragma unroll
    for (int mi = 0; mi < 4; ++mi) {
      int rl = mi * 16 + l15;
      int ph = (rl * 64 + l4 * 16) ^ ((((unsigned)rl >> 1) & 3) << 4);
      a[mi] = *(const bf16x8*)((const char*)&As[cur][0] + ph);
    }
#pragma unroll
    for (int ni = 0; ni < 2; ++ni) {
      int rl = wc + ni * 16 + l15;
      int ph = (rl * 64 + l4 * 16) ^ ((((unsigned)rl >> 1) & 3) << 4);
      b[ni] = *(const bf16x8*)((const char*)&Bs[cur][0] + ph);
    }
#pragma unroll
    for (int mi = 0; mi < 4; ++mi)
#pragma unroll
      for (int ni = 0; ni < 2; ++ni)
        acc[mi][ni] = __builtin_amdgcn_mfma_f32_16x16x32_bf16(a[mi], b[ni], acc[mi][ni], 0, 0, 0);
    __syncthreads();
  }

#pragma unroll
  for (int mi = 0; mi < 4; ++mi) {
#pragma unroll
    for (int ni = 0; ni < 2; ++ni) {
      int gm = bm + mi * 16 + l4 * 4;
      int gn = bn + wc + ni * 16 + l15;
      float bval = bias[gn];
#pragma unroll
      for (int q = 0; q < 4; ++q)
        Cf[(size_t)(gm + q) * N + gn] = (acc[mi][ni][q] + bval) * scale;
    }
  }
}

// ---------------- GEMM2: 256x256 tile, BK=32, reg-prefetch pipeline, fused aggregation ------
// A: value bf16 (2048 x 1024), W: Wv bf16 (32768 x 1024)
// X[b,h,s,d] = scale * sum_r attn[m,h,r] * (A[m,:]@W[h*2048+d*32+r,:] + bias)
__global__ __launch_bounds__(512, 4) void gemm2_k(const unsigned short* __restrict__ A,
                                                  const unsigned short* __restrict__ W,
                                                  const float* __restrict__ bias, float scale,
                                                  const float* __restrict__ attn,
                                                  unsigned short* __restrict__ X) {
  constexpr int K = 1024, BK = 32, NK = K / BK;  // 32 K-tiles
  __shared__ unsigned short As[2][256 * BK];  // 16 KB each
  __shared__ unsigned short Bs[2][256 * BK];  // 64 KB total -> 2 blocks/CU
  const int tid = threadIdx.x;
  const int wid = tid >> 6, lane = tid & 63;
  const int l15 = lane & 15, l4 = lane >> 4;
  const int wm = wid >> 2, wn = wid & 3;

  // XCD-aware bijective swizzle: each XCD gets a contiguous 16-col-tile strip (B-panel L2 reuse)
  int orig = blockIdx.x;
  int swz = (orig & 7) * 128 + (orig >> 3);
  const int bm = (swz & 7) * 256, bn = (swz >> 3) * 256;

  auto stageA = [&](int buf, int kt) {
#pragma unroll
    for (int i = 0; i < 2; ++i) {
      int c = i * 512 + tid;  // 1024 chunks of 16B; tile = 256 rows x 4 chunks
      int row = c >> 2, ch = c & 3;
      int sch = ch ^ ((row >> 1) & 3);  // inverse swizzle on SOURCE (rule #21)
      GLOAD_LDS16(A + (size_t)(bm + row) * K + kt * BK + sch * 8, &As[buf][c * 8]);
    }
  };
  auto stageB = [&](int buf, int kt) {
#pragma unroll
    for (int i = 0; i < 2; ++i) {
      int c = i * 512 + tid;
      int row = c >> 2, ch = c & 3;
      int sch = ch ^ ((row >> 1) & 3);
      GLOAD_LDS16(W + (size_t)(bn + row) * K + kt * BK + sch * 8, &Bs[buf][c * 8]);
    }
  };

  f32x4 acc[8][4];
#pragma unroll
  for (int i = 0; i < 8; ++i)
#pragma unroll
    for (int j = 0; j < 4; ++j) acc[i][j] = (f32x4){0.f, 0.f, 0.f, 0.f};

  bf16x8 a0[8], b0[4], a1[8], b1[4];

#define LOAD_FRAGS(aF, bF, buf)                                                         \
  do {                                                                                  \
    _Pragma("unroll") for (int nf = 0; nf < 4; ++nf) {                                  \
      int rl = wn * 64 + nf * 16 + l15;                                                 \
      int ph = (rl * 64 + l4 * 16) ^ ((((unsigned)rl >> 1) & 3) << 4);                  \
      bF[nf] = *(const bf16x8*)((const char*)&Bs[buf][0] + ph);                         \
    }                                                                                   \
    _Pragma("unroll") for (int mf = 0; mf < 8; ++mf) {                                  \
      int rl = wm * 128 + mf * 16 + l15;                                                \
      int ph = (rl * 64 + l4 * 16) ^ ((((unsigned)rl >> 1) & 3) << 4);                  \
      aF[mf] = *(const bf16x8*)((const char*)&As[buf][0] + ph);                         \
    }                                                                                   \
  } while (0)

#define MFMA_CLUSTER(aF, bF)                                                            \
  do {                                                                                  \
    __builtin_amdgcn_s_setprio(1);                                                      \
    _Pragma("unroll") for (int mf = 0; mf < 8; ++mf)                                    \
        _Pragma("unroll") for (int nf = 0; nf < 4; ++nf)                                \
            acc[mf][nf] =                                                               \
        __builtin_amdgcn_mfma_f32_16x16x32_bf16(aF[mf], bF[nf], acc[mf][nf], 0, 0, 0);  \
    __builtin_amdgcn_s_setprio(0);                                                      \
  } while (0)

  // prologue: stage tiles 0,1; wait tile 0 (counted); load tile-0 fragments
  stageA(0, 0); stageB(0, 0);
  stageA(1, 1); stageB(1, 1);
  asm volatile("s_waitcnt vmcnt(4)" ::: "memory");
  __builtin_amdgcn_s_barrier();
  LOAD_FRAGS(a0, b0, 0);
  asm volatile("s_waitcnt lgkmcnt(0)" ::: "memory");

  for (int T = 0; T < NK; T += 2) {
    // even: MFMA on (a0,b0)=tile T; prefetch tile T+1 frags; stage tile T+2 -> buf0
    asm volatile("s_waitcnt vmcnt(0)" ::: "memory");  // stage(T+1) landed (issued 1 iter ago)
    __builtin_amdgcn_s_barrier();
    if (T + 2 < NK) { stageA(0, T + 2); stageB(0, T + 2); }
    LOAD_FRAGS(a1, b1, 1);  // tile T+1 (T+1 <= 31 always)
    MFMA_CLUSTER(a0, b0);
    asm volatile("s_waitcnt lgkmcnt(0)" ::: "memory");  // frag reads done before next barrier

    // odd: MFMA on (a1,b1)=tile T+1; prefetch tile T+2 frags; stage tile T+3 -> buf1
    asm volatile("s_waitcnt vmcnt(0)" ::: "memory");  // stage(T+2) landed
    __builtin_amdgcn_s_barrier();
    if (T + 3 < NK) { stageA(1, T + 3); stageB(1, T + 3); }
    if (T + 2 < NK) LOAD_FRAGS(a0, b0, 0);  // tile T+2
    MFMA_CLUSTER(a1, b1);
    asm volatile("s_waitcnt lgkmcnt(0)" ::: "memory");
  }

  // ---- fused rule-aggregation epilogue (per-mf to bound register pressure) ----
  const int h = bn >> 11;                          // 2048 cols per head
  const int dbase = ((bn & 2047) + wn * 64) >> 5;  // even
#pragma unroll
  for (int mf = 0; mf < 8; ++mf) {
    int gm0 = bm + wm * 128 + mf * 16 + l4 * 4;
    float red[4][2];
#pragma unroll
    for (int q = 0; q < 4; ++q) { red[q][0] = 0.f; red[q][1] = 0.f; }
#pragma unroll
    for (int nf = 0; nf < 4; ++nf) {
      int col = bn + wn * 64 + nf * 16 + l15;
      float bval = bias[col];
      int r = (nf & 1) * 16 + l15;
      int g = nf >> 1;
#pragma unroll
      for (int q = 0; q < 4; ++q) {
        float w = attn[(size_t)(gm0 + q) * 512 + h * 32 + r];
        red[q][g] += (acc[mf][nf][q] + bval) * w;
      }
    }
#pragma unroll
    for (int q = 0; q < 4; ++q)
#pragma unroll
      for (int g = 0; g < 2; ++g) {
        float vv = red[q][g];
        for (int mask = 1; mask < 16; mask <<= 1) vv += __shfl_xor(vv, mask);
        red[q][g] = vv * scale;
      }
    if (l15 == 0) {
#pragma unroll
      for (int q = 0; q < 4; ++q) {
        int m = gm0 + q;
        int bb = m >> 10, s = m & 1023;
        size_t base = (((size_t)(bb * 16 + h)) * 1024 + s) * 64;
        unsigned lo = f32_to_bf16_rne(red[q][0]);
        unsigned hi = f32_to_bf16_rne(red[q][1]);
        ((unsigned*)X)[(base + dbase) >> 1] = lo | (hi << 16);
      }
    }
  }
#undef LOAD_FRAGS
#undef MFMA_CLUSTER
}

extern "C" void kernel_launch(void* const* d_in, const int* in_sizes, int n_in, void* d_out,
                              int out_size, void* d_ws, size_t ws_size, hipStream_t stream) {
  const float* query = (const float*)d_in[0];
  const float* value = (const float*)d_in[2];
  const float* rk = (const float*)d_in[3];
  const float* rw = (const float*)d_in[4];
  const float* Wq = (const float*)d_in[5];
  const float* bq = (const float*)d_in[6];
  const float* Wv = (const float*)d_in[7];
  const float* bv = (const float*)d_in[8];
  const float* Wo = (const float*)d_in[9];
  const float* bo = (const float*)d_in[10];
  float* out = (float*)d_out;

  const float scale = 0.125f;

  char* p = (char*)d_ws;
  unsigned short* Wv_b = (unsigned short*)p; p += (size_t)33554432 * 2;
  unsigned short* Aq_b = (unsigned short*)p; p += (size_t)2097152 * 2;
  unsigned short* Av_b = (unsigned short*)p; p += (size_t)2097152 * 2;
  unsigned short* Wq_b = (unsigned short*)p; p += (size_t)1048576 * 2;
  unsigned short* Wo_b = (unsigned short*)p; p += (size_t)1048576 * 2;
  float* qf = (float*)p;   p += (size_t)2097152 * 4;
  float* attn = (float*)p; p += (size_t)1048576 * 4;
  unsigned short* X = (unsigned short*)p;

  cvt_all<<<19456, 256, 0, stream>>>(Wv, query, value, Wq, Wo, Wv_b, Aq_b, Av_b, Wq_b, Wo_b);

  // GEMM1: qf = (query @ Wq^T + bq) * scale   (2048 x 1024), 256 blocks
  gemm_bt64<<<dim3(8, 32), 256, 0, stream>>>(Aq_b, Wq_b, bq, scale, 2048, 1024, 1024, qf);
  fuzzy_softmax_k<<<4096, 256, 0, stream>>>(qf, rk, rw, attn);
  // GEMM2 fused (reg-prefetch pipelined 256^2)
  gemm2_k<<<1024, 512, 0, stream>>>(Av_b, Wv_b, bv, scale, attn, X);
  // GEMM3: out = X @ Wo^T + bo
  gemm_bt64<<<dim3(8, 32), 256, 0, stream>>>(X, Wo_b, bo, 1.0f, 2048, 1024, 1024, out);
}

// Round 5
// 326.705 us; speedup vs baseline: 9.5627x; 9.5627x over previous
//
#include <hip/hip_runtime.h>
#include <hip/hip_bf16.h>
#include <cstdint>

typedef float f32x4 __attribute__((ext_vector_type(4)));
typedef short bf16x8 __attribute__((ext_vector_type(8)));

__device__ __forceinline__ unsigned short f32_to_bf16_rne(float f) {
  unsigned int u = __float_as_uint(f);
  return (unsigned short)((u + 0x7FFFu + ((u >> 16) & 1u)) >> 16);
}

#define GLOAD_LDS16(gptr, lptr)                                                             \
  __builtin_amdgcn_global_load_lds((const __attribute__((address_space(1))) unsigned int*)(gptr), \
                                   (__attribute__((address_space(3))) unsigned int*)(lptr), 16, 0, 0)

// ---------------- fused f32 -> bf16 for all 5 operands (8 elems / thread) ----------------
__global__ __launch_bounds__(256) void cvt_all(const float* __restrict__ wv,
                                               const float* __restrict__ q,
                                               const float* __restrict__ v,
                                               const float* __restrict__ wq,
                                               const float* __restrict__ wo,
                                               unsigned short* __restrict__ wvb,
                                               unsigned short* __restrict__ qb,
                                               unsigned short* __restrict__ vb,
                                               unsigned short* __restrict__ wqb,
                                               unsigned short* __restrict__ wob) {
  int i = blockIdx.x * 256 + threadIdx.x;  // chunk of 8 floats
  const float* src;
  unsigned short* dst;
  int off;
  if (i < 4194304)      { src = wv; dst = wvb; off = i; }
  else if (i < 4456448) { src = q;  dst = qb;  off = i - 4194304; }
  else if (i < 4718592) { src = v;  dst = vb;  off = i - 4456448; }
  else if (i < 4849664) { src = wq; dst = wqb; off = i - 4718592; }
  else                  { src = wo; dst = wob; off = i - 4849664; }
  const float4* s = (const float4*)src;
  float4 a = s[2 * off], b = s[2 * off + 1];
  uint4 o;
  o.x = (unsigned)f32_to_bf16_rne(a.x) | ((unsigned)f32_to_bf16_rne(a.y) << 16);
  o.y = (unsigned)f32_to_bf16_rne(a.z) | ((unsigned)f32_to_bf16_rne(a.w) << 16);
  o.z = (unsigned)f32_to_bf16_rne(b.x) | ((unsigned)f32_to_bf16_rne(b.y) << 16);
  o.w = (unsigned)f32_to_bf16_rne(b.z) | ((unsigned)f32_to_bf16_rne(b.w) << 16);
  ((uint4*)dst)[off] = o;
}

// ---------------- fuzzy membership + softmax over rules ----------------
__global__ __launch_bounds__(256) void fuzzy_softmax_k(const float* __restrict__ qf,
                                                       const float* __restrict__ rk,
                                                       const float* __restrict__ rw,
                                                       float* __restrict__ attn) {
  int p = blockIdx.x * 8 + (threadIdx.x >> 5);
  int r = threadIdx.x & 31;
  int m = p >> 4;
  int h = p & 15;
  const float* qrow = qf + (size_t)m * 1024 + h * 64;
  const float* krow = rk + (size_t)(h * 32 + r) * 64;
  const float* wrow = rw + (size_t)(h * 32 + r) * 64;
  float acc = 0.f;
#pragma unroll
  for (int d0 = 0; d0 < 64; d0 += 4) {
    float4 qv = *(const float4*)(qrow + d0);
    float4 kv = *(const float4*)(krow + d0);
    float4 wv = *(const float4*)(wrow + d0);
    float t;
    t = fabsf(qv.x - kv.x) / wv.x; acc += t * t;
    t = fabsf(qv.y - kv.y) / wv.y; acc += t * t;
    t = fabsf(qv.z - kv.z) / wv.z; acc += t * t;
    t = fabsf(qv.w - kv.w) / wv.w; acc += t * t;
  }
  float z = -0.5f * (acc * (1.0f / 64.0f));
  float mx = z;
#pragma unroll
  for (int mask = 16; mask >= 1; mask >>= 1) mx = fmaxf(mx, __shfl_xor(mx, mask));
  float e = __expf(z - mx);
  float s = e;
#pragma unroll
  for (int mask = 16; mask >= 1; mask >>= 1) s += __shfl_xor(s, mask);
  attn[(size_t)m * 512 + h * 32 + r] = e / s;
}

// ---------------- small bf16 GEMM (64x128 tile, 256 blocks): C = (A @ W^T + bias) * scale ----
__global__ __launch_bounds__(256) void gemm_bt64(const unsigned short* __restrict__ A,
                                                 const unsigned short* __restrict__ W,
                                                 const float* __restrict__ bias, float scale,
                                                 int M, int N, int K, float* __restrict__ Cf) {
  constexpr int BM = 64, BN = 128, BK = 32;
  __shared__ unsigned short As[2][BM * BK];
  __shared__ unsigned short Bs[2][BN * BK];
  const int tid = threadIdx.x;
  const int wid = tid >> 6;
  const int lane = tid & 63;
  const int l15 = lane & 15;
  const int l4 = lane >> 4;
  const int bm = blockIdx.y * BM;
  const int bn = blockIdx.x * BN;
  const int wc = wid * 32;

  f32x4 acc[4][2];
#pragma unroll
  for (int i = 0; i < 4; ++i)
#pragma unroll
    for (int j = 0; j < 2; ++j) acc[i][j] = (f32x4){0.f, 0.f, 0.f, 0.f};

  const int nk = K / BK;
  auto stage = [&](int buf, int kt) {
    {
      int c = tid;
      int row = c >> 2, ch = c & 3;
      int sch = ch ^ ((row >> 1) & 3);
      GLOAD_LDS16(A + (size_t)(bm + row) * K + kt * BK + sch * 8, &As[buf][c * 8]);
    }
#pragma unroll
    for (int i = 0; i < 2; ++i) {
      int c = i * 256 + tid;
      int row = c >> 2, ch = c & 3;
      int sch = ch ^ ((row >> 1) & 3);
      GLOAD_LDS16(W + (size_t)(bn + row) * K + kt * BK + sch * 8, &Bs[buf][c * 8]);
    }
  };

  stage(0, 0);
  __syncthreads();

  for (int kt = 0; kt < nk; ++kt) {
    const int cur = kt & 1;
    if (kt + 1 < nk) stage(cur ^ 1, kt + 1);
    bf16x8 a[4], b[2];
#pragma unroll
    for (int mi = 0; mi < 4; ++mi) {
      int rl = mi * 16 + l15;
      int ph = (rl * 64 + l4 * 16) ^ ((((unsigned)rl >> 1) & 3) << 4);
      a[mi] = *(const bf16x8*)((const char*)&As[cur][0] + ph);
    }
#pragma unroll
    for (int ni = 0; ni < 2; ++ni) {
      int rl = wc + ni * 16 + l15;
      int ph = (rl * 64 + l4 * 16) ^ ((((unsigned)rl >> 1) & 3) << 4);
      b[ni] = *(const bf16x8*)((const char*)&Bs[cur][0] + ph);
    }
#pragma unroll
    for (int mi = 0; mi < 4; ++mi)
#pragma unroll
      for (int ni = 0; ni < 2; ++ni)
        acc[mi][ni] = __builtin_amdgcn_mfma_f32_16x16x32_bf16(a[mi], b[ni], acc[mi][ni], 0, 0, 0);
    __syncthreads();
  }

#pragma unroll
  for (int mi = 0; mi < 4; ++mi) {
#pragma unroll
    for (int ni = 0; ni < 2; ++ni) {
      int gm = bm + mi * 16 + l4 * 4;
      int gn = bn + wc + ni * 16 + l15;
      float bval = bias[gn];
#pragma unroll
      for (int q = 0; q < 4; ++q)
        Cf[(size_t)(gm + q) * N + gn] = (acc[mi][ni][q] + bval) * scale;
    }
  }
}

// ---------------- GEMM2: 256x256 tile, BK=32, 4-buf pipeline + interleaved a-reload ----------
// A: value bf16 (2048 x 1024), W: Wv bf16 (32768 x 1024)
// X[b,h,s,d] = scale * sum_r attn[m,h,r] * (A[m,:]@W[h*2048+d*32+r,:] + bias)
// vmcnt accounting: each tile-stage = 4 global_load_lds. In BODY the queue holds
// stage(T+1)=4 (oldest) + stage(T+2)=4 (new) -> vmcnt(4) waits exactly for tile T+1.
__global__ __launch_bounds__(512) void gemm2_k(const unsigned short* __restrict__ A,
                                               const unsigned short* __restrict__ W,
                                               const float* __restrict__ bias, float scale,
                                               const float* __restrict__ attn,
                                               unsigned short* __restrict__ X) {
  constexpr int K = 1024, BK = 32, NK = K / BK;  // 32 K-tiles
  extern __shared__ unsigned short lds[];  // A: 4 bufs x 8192, B: 4 bufs x 8192 => 128 KB
  unsigned short* Asl = lds;
  unsigned short* Bsl = lds + 32768;
  const int tid = threadIdx.x;
  const int wid = tid >> 6, lane = tid & 63;
  const int l15 = lane & 15, l4 = lane >> 4;
  const int wm = wid >> 2, wn = wid & 3;

  // XCD-aware bijective swizzle: contiguous col-tile strip per XCD (B-panel L2 reuse)
  int orig = blockIdx.x;
  int swz = (orig & 7) * 128 + (orig >> 3);
  const int bm = (swz & 7) * 256, bn = (swz >> 3) * 256;

  auto stageA = [&](int buf, int kt) {
#pragma unroll
    for (int i = 0; i < 2; ++i) {
      int c = i * 512 + tid;  // 1024 chunks of 16B; tile = 256 rows x 4 chunks
      int row = c >> 2, ch = c & 3;
      int sch = ch ^ ((row >> 1) & 3);  // inverse swizzle on SOURCE (rule #21)
      GLOAD_LDS16(A + (size_t)(bm + row) * K + kt * BK + sch * 8, Asl + buf * 8192 + c * 8);
    }
  };
  auto stageB = [&](int buf, int kt) {
#pragma unroll
    for (int i = 0; i < 2; ++i) {
      int c = i * 512 + tid;
      int row = c >> 2, ch = c & 3;
      int sch = ch ^ ((row >> 1) & 3);
      GLOAD_LDS16(W + (size_t)(bn + row) * K + kt * BK + sch * 8, Bsl + buf * 8192 + c * 8);
    }
  };

  f32x4 acc[8][4];
#pragma unroll
  for (int i = 0; i < 8; ++i)
#pragma unroll
    for (int j = 0; j < 4; ++j) acc[i][j] = (f32x4){0.f, 0.f, 0.f, 0.f};

  bf16x8 a[8], bC[4], bN[4];

  // BODY(Tt): computes tile Tt using a[] + bCur; stages tile Tt+2; reloads a[] and bNxt
  // with tile Tt+1's fragments, ds_reads interleaved into the MFMA cluster (WAR-pinned).
#define BODY(bCur, bNxt, Tt)                                                              \
  do {                                                                                    \
    stageA((Tt + 2) & 3, Tt + 2);                                                         \
    stageB((Tt + 2) & 3, Tt + 2);                                                         \
    asm volatile("s_waitcnt vmcnt(4)" ::: "memory"); /* tile Tt+1 landed; Tt+2 in flight */\
    __builtin_amdgcn_s_barrier();                                                         \
    {                                                                                     \
      const char* _bb = (const char*)(Bsl + ((Tt + 1) & 3) * 8192);                       \
      const char* _ab = (const char*)(Asl + ((Tt + 1) & 3) * 8192);                       \
      _Pragma("unroll") for (int nf = 0; nf < 4; ++nf) {                                  \
        int rl = wn * 64 + nf * 16 + l15;                                                 \
        int ph = (rl * 64 + l4 * 16) ^ ((((unsigned)rl >> 1) & 3) << 4);                  \
        bNxt[nf] = *(const bf16x8*)(_bb + ph);                                            \
      }                                                                                   \
      __builtin_amdgcn_s_setprio(1);                                                      \
      _Pragma("unroll") for (int mf = 0; mf < 8; ++mf) {                                  \
        _Pragma("unroll") for (int nf = 0; nf < 4; ++nf)                                  \
          acc[mf][nf] =                                                                   \
              __builtin_amdgcn_mfma_f32_16x16x32_bf16(a[mf], bCur[nf], acc[mf][nf], 0, 0, 0); \
        int rl = wm * 128 + mf * 16 + l15;                                                \
        int ph = (rl * 64 + l4 * 16) ^ ((((unsigned)rl >> 1) & 3) << 4);                  \
        a[mf] = *(const bf16x8*)(_ab + ph);                                               \
      }                                                                                   \
      __builtin_amdgcn_s_setprio(0);                                                      \
    }                                                                                     \
    asm volatile("s_waitcnt lgkmcnt(0)" ::: "memory");                                    \
    __builtin_amdgcn_sched_barrier(0);                                                    \
  } while (0)

  // prologue: stage tiles 0,1 (8 loads); vmcnt(4) -> tile 0's 4 landed; load tile-0 frags
  stageA(0, 0); stageB(0, 0);
  stageA(1, 1); stageB(1, 1);
  asm volatile("s_waitcnt vmcnt(4)" ::: "memory");
  __builtin_amdgcn_s_barrier();
#pragma unroll
  for (int nf = 0; nf < 4; ++nf) {
    int rl = wn * 64 + nf * 16 + l15;
    int ph = (rl * 64 + l4 * 16) ^ ((((unsigned)rl >> 1) & 3) << 4);
    bC[nf] = *(const bf16x8*)((const char*)Bsl + ph);
  }
#pragma unroll
  for (int mf = 0; mf < 8; ++mf) {
    int rl = wm * 128 + mf * 16 + l15;
    int ph = (rl * 64 + l4 * 16) ^ ((((unsigned)rl >> 1) & 3) << 4);
    a[mf] = *(const bf16x8*)((const char*)Asl + ph);
  }
  asm volatile("s_waitcnt lgkmcnt(0)" ::: "memory");
  __builtin_amdgcn_sched_barrier(0);

  // main loop: tiles 0..29 (stages reach tile 31; no guards needed)
  for (int T = 0; T < 28; T += 2) {
    BODY(bC, bN, T);
    BODY(bN, bC, (T + 1));
  }
  BODY(bC, bN, 28);  // computes 28, stages 30, prefetches 29
  BODY(bN, bC, 29);  // computes 29, stages 31, prefetches 30

  // tail: tile 30 (no staging; drain), then tile 31
  asm volatile("s_waitcnt vmcnt(0)" ::: "memory");
  __builtin_amdgcn_s_barrier();
  {
    const char* _bb = (const char*)(Bsl + 3 * 8192);  // tile 31 -> buf 3
    const char* _ab = (const char*)(Asl + 3 * 8192);
#pragma unroll
    for (int nf = 0; nf < 4; ++nf) {
      int rl = wn * 64 + nf * 16 + l15;
      int ph = (rl * 64 + l4 * 16) ^ ((((unsigned)rl >> 1) & 3) << 4);
      bN[nf] = *(const bf16x8*)(_bb + ph);
    }
    __builtin_amdgcn_s_setprio(1);
#pragma unroll
    for (int mf = 0; mf < 8; ++mf) {
#pragma unroll
      for (int nf = 0; nf < 4; ++nf)
        acc[mf][nf] = __builtin_amdgcn_mfma_f32_16x16x32_bf16(a[mf], bC[nf], acc[mf][nf], 0, 0, 0);
      int rl = wm * 128 + mf * 16 + l15;
      int ph = (rl * 64 + l4 * 16) ^ ((((unsigned)rl >> 1) & 3) << 4);
      a[mf] = *(const bf16x8*)(_ab + ph);
    }
    __builtin_amdgcn_s_setprio(0);
  }
  asm volatile("s_waitcnt lgkmcnt(0)" ::: "memory");
  __builtin_amdgcn_sched_barrier(0);
  __builtin_amdgcn_s_setprio(1);
#pragma unroll
  for (int mf = 0; mf < 8; ++mf)
#pragma unroll
    for (int nf = 0; nf < 4; ++nf)
      acc[mf][nf] = __builtin_amdgcn_mfma_f32_16x16x32_bf16(a[mf], bN[nf], acc[mf][nf], 0, 0, 0);
  __builtin_amdgcn_s_setprio(0);
#undef BODY

  // ---- fused rule-aggregation epilogue (per-mf to bound register pressure) ----
  const int h = bn >> 11;                          // 2048 cols per head
  const int dbase = ((bn & 2047) + wn * 64) >> 5;  // even
#pragma unroll
  for (int mf = 0; mf < 8; ++mf) {
    int gm0 = bm + wm * 128 + mf * 16 + l4 * 4;
    float red[4][2];
#pragma unroll
    for (int q = 0; q < 4; ++q) { red[q][0] = 0.f; red[q][1] = 0.f; }
#pragma unroll
    for (int nf = 0; nf < 4; ++nf) {
      int col = bn + wn * 64 + nf * 16 + l15;
      float bval = bias[col];
      int r = (nf & 1) * 16 + l15;
      int g = nf >> 1;
#pragma unroll
      for (int q = 0; q < 4; ++q) {
        float w = attn[(size_t)(gm0 + q) * 512 + h * 32 + r];
        red[q][g] += (acc[mf][nf][q] + bval) * w;
      }
    }
#pragma unroll
    for (int q = 0; q < 4; ++q)
#pragma unroll
      for (int g = 0; g < 2; ++g) {
        float vv = red[q][g];
        for (int mask = 1; mask < 16; mask <<= 1) vv += __shfl_xor(vv, mask);
        red[q][g] = vv * scale;
      }
    if (l15 == 0) {
#pragma unroll
      for (int q = 0; q < 4; ++q) {
        int m = gm0 + q;
        int bb = m >> 10, s = m & 1023;
        size_t base = (((size_t)(bb * 16 + h)) * 1024 + s) * 64;
        unsigned lo = f32_to_bf16_rne(red[q][0]);
        unsigned hi = f32_to_bf16_rne(red[q][1]);
        ((unsigned*)X)[(base + dbase) >> 1] = lo | (hi << 16);
      }
    }
  }
}

extern "C" void kernel_launch(void* const* d_in, const int* in_sizes, int n_in, void* d_out,
                              int out_size, void* d_ws, size_t ws_size, hipStream_t stream) {
  const float* query = (const float*)d_in[0];
  const float* value = (const float*)d_in[2];
  const float* rk = (const float*)d_in[3];
  const float* rw = (const float*)d_in[4];
  const float* Wq = (const float*)d_in[5];
  const float* bq = (const float*)d_in[6];
  const float* Wv = (const float*)d_in[7];
  const float* bv = (const float*)d_in[8];
  const float* Wo = (const float*)d_in[9];
  const float* bo = (const float*)d_in[10];
  float* out = (float*)d_out;

  const float scale = 0.125f;

  char* p = (char*)d_ws;
  unsigned short* Wv_b = (unsigned short*)p; p += (size_t)33554432 * 2;
  unsigned short* Aq_b = (unsigned short*)p; p += (size_t)2097152 * 2;
  unsigned short* Av_b = (unsigned short*)p; p += (size_t)2097152 * 2;
  unsigned short* Wq_b = (unsigned short*)p; p += (size_t)1048576 * 2;
  unsigned short* Wo_b = (unsigned short*)p; p += (size_t)1048576 * 2;
  float* qf = (float*)p;   p += (size_t)2097152 * 4;
  float* attn = (float*)p; p += (size_t)1048576 * 4;
  unsigned short* X = (unsigned short*)p;

  cvt_all<<<19456, 256, 0, stream>>>(Wv, query, value, Wq, Wo, Wv_b, Aq_b, Av_b, Wq_b, Wo_b);

  // GEMM1: qf = (query @ Wq^T + bq) * scale   (2048 x 1024), 256 blocks
  gemm_bt64<<<dim3(8, 32), 256, 0, stream>>>(Aq_b, Wq_b, bq, scale, 2048, 1024, 1024, qf);
  fuzzy_softmax_k<<<4096, 256, 0, stream>>>(qf, rk, rw, attn);
  // GEMM2 fused (4-buf pipelined 256^2, 128 KB dynamic LDS)
  hipFuncSetAttribute((const void*)gemm2_k, hipFuncAttributeMaxDynamicSharedMemorySize, 131072);
  gemm2_k<<<1024, 512, 131072, stream>>>(Av_b, Wv_b, bv, scale, attn, X);
  // GEMM3: out = X @ Wo^T + bo
  gemm_bt64<<<dim3(8, 32), 256, 0, stream>>>(X, Wo_b, bo, 1.0f, 2048, 1024, 1024, out);
}

// Round 6
// 238.496 us; speedup vs baseline: 13.0995x; 1.3699x over previous
//
#include <hip/hip_runtime.h>
#include <hip/hip_bf16.h>
#include <cstdint>

typedef float f32x4 __attribute__((ext_vector_type(4)));
typedef short bf16x8 __attribute__((ext_vector_type(8)));

__device__ __forceinline__ unsigned short f32_to_bf16_rne(float f) {
  unsigned int u = __float_as_uint(f);
  return (unsigned short)((u + 0x7FFFu + ((u >> 16) & 1u)) >> 16);
}

#define GLOAD_LDS16(gptr, lptr)                                                             \
  __builtin_amdgcn_global_load_lds((const __attribute__((address_space(1))) unsigned int*)(gptr), \
                                   (__attribute__((address_space(3))) unsigned int*)(lptr), 16, 0, 0)

// ---------------- fused f32 -> bf16 for all 5 operands (8 elems / thread) ----------------
__global__ __launch_bounds__(256) void cvt_all(const float* __restrict__ wv,
                                               const float* __restrict__ q,
                                               const float* __restrict__ v,
                                               const float* __restrict__ wq,
                                               const float* __restrict__ wo,
                                               unsigned short* __restrict__ wvb,
                                               unsigned short* __restrict__ qb,
                                               unsigned short* __restrict__ vb,
                                               unsigned short* __restrict__ wqb,
                                               unsigned short* __restrict__ wob) {
  int i = blockIdx.x * 256 + threadIdx.x;  // chunk of 8 floats
  const float* src;
  unsigned short* dst;
  int off;
  if (i < 4194304)      { src = wv; dst = wvb; off = i; }
  else if (i < 4456448) { src = q;  dst = qb;  off = i - 4194304; }
  else if (i < 4718592) { src = v;  dst = vb;  off = i - 4456448; }
  else if (i < 4849664) { src = wq; dst = wqb; off = i - 4718592; }
  else                  { src = wo; dst = wob; off = i - 4849664; }
  const float4* s = (const float4*)src;
  float4 a = s[2 * off], b = s[2 * off + 1];
  uint4 o;
  o.x = (unsigned)f32_to_bf16_rne(a.x) | ((unsigned)f32_to_bf16_rne(a.y) << 16);
  o.y = (unsigned)f32_to_bf16_rne(a.z) | ((unsigned)f32_to_bf16_rne(a.w) << 16);
  o.z = (unsigned)f32_to_bf16_rne(b.x) | ((unsigned)f32_to_bf16_rne(b.y) << 16);
  o.w = (unsigned)f32_to_bf16_rne(b.z) | ((unsigned)f32_to_bf16_rne(b.w) << 16);
  ((uint4*)dst)[off] = o;
}

// ---------------- fuzzy membership + softmax: LDS-staged rules, one head per block --------
// grid (16 mchunks, 16 heads), 256 thr. attn[m,h,r] layout (M, H, R).
__global__ __launch_bounds__(256) void fuzzy2_k(const float* __restrict__ qf,
                                                const float* __restrict__ rk,
                                                const float* __restrict__ rw,
                                                float* __restrict__ attn) {
  __shared__ float lk[32][65];  // rule keys, +1 pad -> conflict-free row-per-lane reads
  __shared__ float lc[32][65];  // 0.5/64 / rw^2
  const int tid = threadIdx.x;
  const int h = blockIdx.y;
  const int mbase = blockIdx.x * 128;

  for (int idx = tid; idx < 2048; idx += 256) {
    int r = idx >> 6, d = idx & 63;
    lk[r][d] = rk[(size_t)(h * 32 + r) * 64 + d];
    float w = rw[(size_t)(h * 32 + r) * 64 + d];
    lc[r][d] = 0.0078125f / (w * w);
  }
  __syncthreads();

  const int g = tid >> 5;   // 8 groups of 32 lanes
  const int r = tid & 31;
#pragma unroll 1
  for (int it = 0; it < 16; ++it) {
    int m = mbase + it * 8 + g;
    const float* qrow = qf + (size_t)m * 1024 + h * 64;
    float acc = 0.f;
#pragma unroll
    for (int d0 = 0; d0 < 64; d0 += 4) {
      float4 q4 = *(const float4*)(qrow + d0);
      const float* qp = (const float*)&q4;
#pragma unroll
      for (int j = 0; j < 4; ++j) {
        float diff = qp[j] - lk[r][d0 + j];
        acc += lc[r][d0 + j] * diff * diff;
      }
    }
    float z = -acc;
    float mx = z;
#pragma unroll
    for (int mask = 16; mask >= 1; mask >>= 1) mx = fmaxf(mx, __shfl_xor(mx, mask));
    float e = __expf(z - mx);
    float s = e;
#pragma unroll
    for (int mask = 16; mask >= 1; mask >>= 1) s += __shfl_xor(s, mask);
    attn[(size_t)m * 512 + h * 32 + r] = e / s;
  }
}

// ---------------- small bf16 GEMM (64x128 tile, 256 blocks): C = (A @ W^T + bias) * scale ----
__global__ __launch_bounds__(256) void gemm_bt64(const unsigned short* __restrict__ A,
                                                 const unsigned short* __restrict__ W,
                                                 const float* __restrict__ bias, float scale,
                                                 int M, int N, int K, float* __restrict__ Cf) {
  constexpr int BM = 64, BN = 128, BK = 32;
  __shared__ unsigned short As[2][BM * BK];
  __shared__ unsigned short Bs[2][BN * BK];
  const int tid = threadIdx.x;
  const int wid = tid >> 6;
  const int lane = tid & 63;
  const int l15 = lane & 15;
  const int l4 = lane >> 4;
  const int bm = blockIdx.y * BM;
  const int bn = blockIdx.x * BN;
  const int wc = wid * 32;

  f32x4 acc[4][2];
#pragma unroll
  for (int i = 0; i < 4; ++i)
#pragma unroll
    for (int j = 0; j < 2; ++j) acc[i][j] = (f32x4){0.f, 0.f, 0.f, 0.f};

  const int nk = K / BK;
  auto stage = [&](int buf, int kt) {
    {
      int c = tid;
      int row = c >> 2, ch = c & 3;
      int sch = ch ^ ((row >> 1) & 3);
      GLOAD_LDS16(A + (size_t)(bm + row) * K + kt * BK + sch * 8, &As[buf][c * 8]);
    }
#pragma unroll
    for (int i = 0; i < 2; ++i) {
      int c = i * 256 + tid;
      int row = c >> 2, ch = c & 3;
      int sch = ch ^ ((row >> 1) & 3);
      GLOAD_LDS16(W + (size_t)(bn + row) * K + kt * BK + sch * 8, &Bs[buf][c * 8]);
    }
  };

  stage(0, 0);
  __syncthreads();

  for (int kt = 0; kt < nk; ++kt) {
    const int cur = kt & 1;
    if (kt + 1 < nk) stage(cur ^ 1, kt + 1);
    bf16x8 a[4], b[2];
#pragma unroll
    for (int mi = 0; mi < 4; ++mi) {
      int rl = mi * 16 + l15;
      int ph = (rl * 64 + l4 * 16) ^ ((((unsigned)rl >> 1) & 3) << 4);
      a[mi] = *(const bf16x8*)((const char*)&As[cur][0] + ph);
    }
#pragma unroll
    for (int ni = 0; ni < 2; ++ni) {
      int rl = wc + ni * 16 + l15;
      int ph = (rl * 64 + l4 * 16) ^ ((((unsigned)rl >> 1) & 3) << 4);
      b[ni] = *(const bf16x8*)((const char*)&Bs[cur][0] + ph);
    }
#pragma unroll
    for (int mi = 0; mi < 4; ++mi)
#pragma unroll
      for (int ni = 0; ni < 2; ++ni)
        acc[mi][ni] = __builtin_amdgcn_mfma_f32_16x16x32_bf16(a[mi], b[ni], acc[mi][ni], 0, 0, 0);
    __syncthreads();
  }

#pragma unroll
  for (int mi = 0; mi < 4; ++mi) {
#pragma unroll
    for (int ni = 0; ni < 2; ++ni) {
      int gm = bm + mi * 16 + l4 * 4;
      int gn = bn + wc + ni * 16 + l15;
      float bval = bias[gn];
#pragma unroll
      for (int q = 0; q < 4; ++q)
        Cf[(size_t)(gm + q) * N + gn] = (acc[mi][ni][q] + bval) * scale;
    }
  }
}

// ---------------- GEMM2: 256x256 tile, BK=32, 4-buf pipeline, fully interleaved reads ------
// A: value bf16 (2048 x 1024), W: Wv bf16 (32768 x 1024)
// X[b,h,s,d] = scale * sum_r attn[m,h,r] * (A[m,:]@W[h*2048+d*32+r,:] + bias)
// vmcnt: 4 gload_lds per tile-stage. BODY(T) issues stage(T+2): queue = stage(T+1)[4] +
// stage(T+2)[4] -> vmcnt(4) waits exactly for tile T+1 (whose frags this BODY reads).
// All 12 ds_reads (4 b-reloads + 8 a-next) are issued INSIDE the MFMA cluster (b via
// register-WAR after last use) so LDS traffic hides under the matrix pipe; the only
// lgkmcnt(0) is the end-of-body drain.
__global__ __launch_bounds__(512) void gemm2_k(const unsigned short* __restrict__ A,
                                               const unsigned short* __restrict__ W,
                                               const float* __restrict__ bias, float scale,
                                               const float* __restrict__ attn,
                                               unsigned short* __restrict__ X) {
  constexpr int K = 1024, BK = 32, NK = K / BK;  // 32 K-tiles
  extern __shared__ unsigned short lds[];  // A: 4 bufs x 8192, B: 4 bufs x 8192 => 128 KB
  unsigned short* Asl = lds;
  unsigned short* Bsl = lds + 32768;
  const int tid = threadIdx.x;
  const int wid = tid >> 6, lane = tid & 63;
  const int l15 = lane & 15, l4 = lane >> 4;
  const int wm = wid >> 2, wn = wid & 3;

  // XCD-aware bijective swizzle: contiguous col-tile strip per XCD (B-panel L2 reuse)
  int orig = blockIdx.x;
  int swz = (orig & 7) * 128 + (orig >> 3);
  const int bm = (swz & 7) * 256, bn = (swz >> 3) * 256;

  auto stageA = [&](int buf, int kt) {
#pragma unroll
    for (int i = 0; i < 2; ++i) {
      int c = i * 512 + tid;  // 1024 chunks of 16B; tile = 256 rows x 4 chunks
      int row = c >> 2, ch = c & 3;
      int sch = ch ^ ((row >> 1) & 3);  // inverse swizzle on SOURCE (rule #21)
      GLOAD_LDS16(A + (size_t)(bm + row) * K + kt * BK + sch * 8, Asl + buf * 8192 + c * 8);
    }
  };
  auto stageB = [&](int buf, int kt) {
#pragma unroll
    for (int i = 0; i < 2; ++i) {
      int c = i * 512 + tid;
      int row = c >> 2, ch = c & 3;
      int sch = ch ^ ((row >> 1) & 3);
      GLOAD_LDS16(W + (size_t)(bn + row) * K + kt * BK + sch * 8, Bsl + buf * 8192 + c * 8);
    }
  };

  f32x4 acc[8][4];
#pragma unroll
  for (int i = 0; i < 8; ++i)
#pragma unroll
    for (int j = 0; j < 4; ++j) acc[i][j] = (f32x4){0.f, 0.f, 0.f, 0.f};

  bf16x8 a0[8], a1[8], b[4];

#define FRAG_PH(rl) (((rl) * 64 + l4 * 16) ^ ((((unsigned)(rl) >> 1) & 3) << 4))

  // BODY: compute tile Tt from (aC, b); stage Tt+2; reload b[] and aN[] with tile Tt+1's
  // fragments, all reads interleaved into the MFMA cluster.
#define BODY(aC, aN, Tt, DO_STAGE, WN)                                                    \
  do {                                                                                    \
    if (DO_STAGE) {                                                                       \
      stageA(((Tt) + 2) & 3, (Tt) + 2);                                                   \
      stageB(((Tt) + 2) & 3, (Tt) + 2);                                                   \
    }                                                                                     \
    asm volatile("s_waitcnt vmcnt(" #WN ")" ::: "memory");                                \
    __builtin_amdgcn_s_barrier();                                                         \
    {                                                                                     \
      const char* _ab = (const char*)(Asl + (((Tt) + 1) & 3) * 8192);                     \
      const char* _bb = (const char*)(Bsl + (((Tt) + 1) & 3) * 8192);                     \
      __builtin_amdgcn_s_setprio(1);                                                      \
      _Pragma("unroll") for (int nf = 0; nf < 4; ++nf) {                                  \
        _Pragma("unroll") for (int mf = 0; mf < 8; ++mf)                                  \
          acc[mf][nf] =                                                                   \
              __builtin_amdgcn_mfma_f32_16x16x32_bf16(aC[mf], b[nf], acc[mf][nf], 0, 0, 0); \
        {                                                                                 \
          int rl = wn * 64 + nf * 16 + l15;                                               \
          b[nf] = *(const bf16x8*)(_bb + FRAG_PH(rl));                                    \
        }                                                                                 \
        _Pragma("unroll") for (int t = 0; t < 2; ++t) {                                   \
          int mf2 = nf * 2 + t;                                                           \
          int rl = wm * 128 + mf2 * 16 + l15;                                             \
          aN[mf2] = *(const bf16x8*)(_ab + FRAG_PH(rl));                                  \
        }                                                                                 \
      }                                                                                   \
      __builtin_amdgcn_s_setprio(0);                                                      \
    }                                                                                     \
    asm volatile("s_waitcnt lgkmcnt(0)" ::: "memory");                                    \
    __builtin_amdgcn_sched_barrier(0);                                                    \
  } while (0)

  // prologue: stage tiles 0,1 (8 loads); vmcnt(4) -> tile 0 landed; load tile-0 frags
  stageA(0, 0); stageB(0, 0);
  stageA(1, 1); stageB(1, 1);
  asm volatile("s_waitcnt vmcnt(4)" ::: "memory");
  __builtin_amdgcn_s_barrier();
#pragma unroll
  for (int nf = 0; nf < 4; ++nf) {
    int rl = wn * 64 + nf * 16 + l15;
    b[nf] = *(const bf16x8*)((const char*)Bsl + FRAG_PH(rl));
  }
#pragma unroll
  for (int mf = 0; mf < 8; ++mf) {
    int rl = wm * 128 + mf * 16 + l15;
    a0[mf] = *(const bf16x8*)((const char*)Asl + FRAG_PH(rl));
  }
  asm volatile("s_waitcnt lgkmcnt(0)" ::: "memory");
  __builtin_amdgcn_sched_barrier(0);

  // bodies 0..29 (stage reaches tile 31 at body 29)
  for (int T = 0; T < 30; T += 2) {
    BODY(a0, a1, T, 1, 4);
    BODY(a1, a0, (T + 1), 1, 4);
  }
  // body 30: no stage; wait stage(31) (only 4 outstanding); prefetch tile-31 frags
  BODY(a0, a1, 30, 0, 0);
  // tail: tile 31, registers only
  __builtin_amdgcn_s_setprio(1);
#pragma unroll
  for (int nf = 0; nf < 4; ++nf)
#pragma unroll
    for (int mf = 0; mf < 8; ++mf)
      acc[mf][nf] = __builtin_amdgcn_mfma_f32_16x16x32_bf16(a1[mf], b[nf], acc[mf][nf], 0, 0, 0);
  __builtin_amdgcn_s_setprio(0);
#undef BODY
#undef FRAG_PH

  // ---- fused rule-aggregation epilogue (per-mf to bound register pressure) ----
  const int h = bn >> 11;                          // 2048 cols per head
  const int dbase = ((bn & 2047) + wn * 64) >> 5;  // even
#pragma unroll
  for (int mf = 0; mf < 8; ++mf) {
    int gm0 = bm + wm * 128 + mf * 16 + l4 * 4;
    float red[4][2];
#pragma unroll
    for (int q = 0; q < 4; ++q) { red[q][0] = 0.f; red[q][1] = 0.f; }
#pragma unroll
    for (int nf = 0; nf < 4; ++nf) {
      int col = bn + wn * 64 + nf * 16 + l15;
      float bval = bias[col];
      int r = (nf & 1) * 16 + l15;
      int g = nf >> 1;
#pragma unroll
      for (int q = 0; q < 4; ++q) {
        float w = attn[(size_t)(gm0 + q) * 512 + h * 32 + r];
        red[q][g] += (acc[mf][nf][q] + bval) * w;
      }
    }
#pragma unroll
    for (int q = 0; q < 4; ++q)
#pragma unroll
      for (int g = 0; g < 2; ++g) {
        float vv = red[q][g];
        for (int mask = 1; mask < 16; mask <<= 1) vv += __shfl_xor(vv, mask);
        red[q][g] = vv * scale;
      }
    if (l15 == 0) {
#pragma unroll
      for (int q = 0; q < 4; ++q) {
        int m = gm0 + q;
        int bb = m >> 10, s = m & 1023;
        size_t base = (((size_t)(bb * 16 + h)) * 1024 + s) * 64;
        unsigned lo = f32_to_bf16_rne(red[q][0]);
        unsigned hi = f32_to_bf16_rne(red[q][1]);
        ((unsigned*)X)[(base + dbase) >> 1] = lo | (hi << 16);
      }
    }
  }
}

extern "C" void kernel_launch(void* const* d_in, const int* in_sizes, int n_in, void* d_out,
                              int out_size, void* d_ws, size_t ws_size, hipStream_t stream) {
  const float* query = (const float*)d_in[0];
  const float* value = (const float*)d_in[2];
  const float* rk = (const float*)d_in[3];
  const float* rw = (const float*)d_in[4];
  const float* Wq = (const float*)d_in[5];
  const float* bq = (const float*)d_in[6];
  const float* Wv = (const float*)d_in[7];
  const float* bv = (const float*)d_in[8];
  const float* Wo = (const float*)d_in[9];
  const float* bo = (const float*)d_in[10];
  float* out = (float*)d_out;

  const float scale = 0.125f;

  char* p = (char*)d_ws;
  unsigned short* Wv_b = (unsigned short*)p; p += (size_t)33554432 * 2;
  unsigned short* Aq_b = (unsigned short*)p; p += (size_t)2097152 * 2;
  unsigned short* Av_b = (unsigned short*)p; p += (size_t)2097152 * 2;
  unsigned short* Wq_b = (unsigned short*)p; p += (size_t)1048576 * 2;
  unsigned short* Wo_b = (unsigned short*)p; p += (size_t)1048576 * 2;
  float* qf = (float*)p;   p += (size_t)2097152 * 4;
  float* attn = (float*)p; p += (size_t)1048576 * 4;
  unsigned short* X = (unsigned short*)p;

  cvt_all<<<19456, 256, 0, stream>>>(Wv, query, value, Wq, Wo, Wv_b, Aq_b, Av_b, Wq_b, Wo_b);

  // GEMM1: qf = (query @ Wq^T + bq) * scale   (2048 x 1024), 256 blocks
  gemm_bt64<<<dim3(8, 32), 256, 0, stream>>>(Aq_b, Wq_b, bq, scale, 2048, 1024, 1024, qf);
  // fuzzy membership + softmax (LDS-staged rules, one head per block)
  fuzzy2_k<<<dim3(16, 16), 256, 0, stream>>>(qf, rk, rw, attn);
  // GEMM2 fused (4-buf pipelined 256^2, 128 KB dynamic LDS)
  hipFuncSetAttribute((const void*)gemm2_k, hipFuncAttributeMaxDynamicSharedMemorySize, 131072);
  gemm2_k<<<1024, 512, 131072, stream>>>(Av_b, Wv_b, bv, scale, attn, X);
  // GEMM3: out = X @ Wo^T + bo
  gemm_bt64<<<dim3(8, 32), 256, 0, stream>>>(X, Wo_b, bo, 1.0f, 2048, 1024, 1024, out);
}

// Round 7
// 235.164 us; speedup vs baseline: 13.2851x; 1.0142x over previous
//
#include <hip/hip_runtime.h>
#include <hip/hip_bf16.h>
#include <cstdint>

typedef float f32x4 __attribute__((ext_vector_type(4)));
typedef short bf16x8 __attribute__((ext_vector_type(8)));

__device__ __forceinline__ unsigned short f32_to_bf16_rne(float f) {
  unsigned int u = __float_as_uint(f);
  return (unsigned short)((u + 0x7FFFu + ((u >> 16) & 1u)) >> 16);
}

#define GLOAD_LDS16(gptr, lptr)                                                             \
  __builtin_amdgcn_global_load_lds((const __attribute__((address_space(1))) unsigned int*)(gptr), \
                                   (__attribute__((address_space(3))) unsigned int*)(lptr), 16, 0, 0)

// ---------------- fused f32 -> bf16 for all 5 operands (8 elems / thread) ----------------
__global__ __launch_bounds__(256) void cvt_all(const float* __restrict__ wv,
                                               const float* __restrict__ q,
                                               const float* __restrict__ v,
                                               const float* __restrict__ wq,
                                               const float* __restrict__ wo,
                                               unsigned short* __restrict__ wvb,
                                               unsigned short* __restrict__ qb,
                                               unsigned short* __restrict__ vb,
                                               unsigned short* __restrict__ wqb,
                                               unsigned short* __restrict__ wob) {
  int i = blockIdx.x * 256 + threadIdx.x;  // chunk of 8 floats
  const float* src;
  unsigned short* dst;
  int off;
  if (i < 4194304)      { src = wv; dst = wvb; off = i; }
  else if (i < 4456448) { src = q;  dst = qb;  off = i - 4194304; }
  else if (i < 4718592) { src = v;  dst = vb;  off = i - 4456448; }
  else if (i < 4849664) { src = wq; dst = wqb; off = i - 4718592; }
  else                  { src = wo; dst = wob; off = i - 4849664; }
  const float4* s = (const float4*)src;
  float4 a = s[2 * off], b = s[2 * off + 1];
  uint4 o;
  o.x = (unsigned)f32_to_bf16_rne(a.x) | ((unsigned)f32_to_bf16_rne(a.y) << 16);
  o.y = (unsigned)f32_to_bf16_rne(a.z) | ((unsigned)f32_to_bf16_rne(a.w) << 16);
  o.z = (unsigned)f32_to_bf16_rne(b.x) | ((unsigned)f32_to_bf16_rne(b.y) << 16);
  o.w = (unsigned)f32_to_bf16_rne(b.z) | ((unsigned)f32_to_bf16_rne(b.w) << 16);
  ((uint4*)dst)[off] = o;
}

// ---------------- fuzzy membership + softmax: LDS-staged rules, one head per block --------
__global__ __launch_bounds__(256) void fuzzy2_k(const float* __restrict__ qf,
                                                const float* __restrict__ rk,
                                                const float* __restrict__ rw,
                                                float* __restrict__ attn) {
  __shared__ float lk[32][65];
  __shared__ float lc[32][65];
  const int tid = threadIdx.x;
  const int h = blockIdx.y;
  const int mbase = blockIdx.x * 128;

  for (int idx = tid; idx < 2048; idx += 256) {
    int r = idx >> 6, d = idx & 63;
    lk[r][d] = rk[(size_t)(h * 32 + r) * 64 + d];
    float w = rw[(size_t)(h * 32 + r) * 64 + d];
    lc[r][d] = 0.0078125f / (w * w);
  }
  __syncthreads();

  const int g = tid >> 5;
  const int r = tid & 31;
#pragma unroll 1
  for (int it = 0; it < 16; ++it) {
    int m = mbase + it * 8 + g;
    const float* qrow = qf + (size_t)m * 1024 + h * 64;
    float acc = 0.f;
#pragma unroll
    for (int d0 = 0; d0 < 64; d0 += 4) {
      float4 q4 = *(const float4*)(qrow + d0);
      const float* qp = (const float*)&q4;
#pragma unroll
      for (int j = 0; j < 4; ++j) {
        float diff = qp[j] - lk[r][d0 + j];
        acc += lc[r][d0 + j] * diff * diff;
      }
    }
    float z = -acc;
    float mx = z;
#pragma unroll
    for (int mask = 16; mask >= 1; mask >>= 1) mx = fmaxf(mx, __shfl_xor(mx, mask));
    float e = __expf(z - mx);
    float s = e;
#pragma unroll
    for (int mask = 16; mask >= 1; mask >>= 1) s += __shfl_xor(s, mask);
    attn[(size_t)m * 512 + h * 32 + r] = e / s;
  }
}

// ---------------- small bf16 GEMM (64x64 tile, 512 blocks, ~8/CU): C = (A@W^T+b)*scale ----
__global__ __launch_bounds__(256) void gemm_bt64(const unsigned short* __restrict__ A,
                                                 const unsigned short* __restrict__ W,
                                                 const float* __restrict__ bias, float scale,
                                                 int M, int N, int K, float* __restrict__ Cf) {
  constexpr int BK = 32;
  __shared__ unsigned short As[2][64 * BK];
  __shared__ unsigned short Bs[2][64 * BK];
  const int tid = threadIdx.x;
  const int wid = tid >> 6;
  const int lane = tid & 63;
  const int l15 = lane & 15;
  const int l4 = lane >> 4;
  const int bm = blockIdx.y * 64;
  const int bn = blockIdx.x * 64;
  const int wr = (wid >> 1) * 32;
  const int wc = (wid & 1) * 32;

  f32x4 acc[2][2];
#pragma unroll
  for (int i = 0; i < 2; ++i)
#pragma unroll
    for (int j = 0; j < 2; ++j) acc[i][j] = (f32x4){0.f, 0.f, 0.f, 0.f};

  const int nk = K / BK;
  auto stage = [&](int buf, int kt) {
    int c = tid;  // 256 chunks of 16B per 4KB tile
    int row = c >> 2, ch = c & 3;
    int sch = ch ^ ((row >> 1) & 3);
    GLOAD_LDS16(A + (size_t)(bm + row) * K + kt * BK + sch * 8, &As[buf][c * 8]);
    GLOAD_LDS16(W + (size_t)(bn + row) * K + kt * BK + sch * 8, &Bs[buf][c * 8]);
  };

  stage(0, 0);
  __syncthreads();

  for (int kt = 0; kt < nk; ++kt) {
    const int cur = kt & 1;
    if (kt + 1 < nk) stage(cur ^ 1, kt + 1);
    bf16x8 a[2], b[2];
#pragma unroll
    for (int mi = 0; mi < 2; ++mi) {
      int rl = wr + mi * 16 + l15;
      int ph = (rl * 64 + l4 * 16) ^ ((((unsigned)rl >> 1) & 3) << 4);
      a[mi] = *(const bf16x8*)((const char*)&As[cur][0] + ph);
    }
#pragma unroll
    for (int ni = 0; ni < 2; ++ni) {
      int rl = wc + ni * 16 + l15;
      int ph = (rl * 64 + l4 * 16) ^ ((((unsigned)rl >> 1) & 3) << 4);
      b[ni] = *(const bf16x8*)((const char*)&Bs[cur][0] + ph);
    }
#pragma unroll
    for (int mi = 0; mi < 2; ++mi)
#pragma unroll
      for (int ni = 0; ni < 2; ++ni)
        acc[mi][ni] = __builtin_amdgcn_mfma_f32_16x16x32_bf16(a[mi], b[ni], acc[mi][ni], 0, 0, 0);
    __syncthreads();
  }

#pragma unroll
  for (int mi = 0; mi < 2; ++mi) {
#pragma unroll
    for (int ni = 0; ni < 2; ++ni) {
      int gm = bm + wr + mi * 16 + l4 * 4;
      int gn = bn + wc + ni * 16 + l15;
      float bval = bias[gn];
#pragma unroll
      for (int q = 0; q < 4; ++q)
        Cf[(size_t)(gm + q) * N + gn] = (acc[mi][ni][q] + bval) * scale;
    }
  }
}

// ---------------- GEMM2: 128x256 tile, BK=32, 3-buf (72KB -> 2 blocks/CU), fused agg ------
// A: value bf16 (2048 x 1024), W: Wv bf16 (32768 x 1024)
// X[b,h,s,d] = scale * sum_r attn[m,h,r] * (A[m,:]@W[h*2048+d*32+r,:] + bias)
// vmcnt: 3 gload_lds per tile-stage (A 1 + B 2). BODY(T) issues stage(T+2):
// queue = stage(T+1)[3] + stage(T+2)[3] -> vmcnt(3) waits exactly tile T+1.
__global__ __launch_bounds__(512, 4) void gemm2_k(const unsigned short* __restrict__ A,
                                                  const unsigned short* __restrict__ W,
                                                  const float* __restrict__ bias, float scale,
                                                  const float* __restrict__ attn,
                                                  unsigned short* __restrict__ X) {
  constexpr int K = 1024, BK = 32, NK = K / BK;  // 32 K-tiles
  extern __shared__ unsigned short lds[];  // A: 3 x 4096, B: 3 x 8192 ushorts = 72 KB
  unsigned short* Asl = lds;
  unsigned short* Bsl = lds + 3 * 4096;
  const int tid = threadIdx.x;
  const int wid = tid >> 6, lane = tid & 63;
  const int l15 = lane & 15, l4 = lane >> 4;
  const int wm = wid >> 2, wn = wid & 3;  // wave tile 64x64: rows wm*64, cols wn*64

  // XCD-aware bijective swizzle: 16-col-tile strip per XCD
  int orig = blockIdx.x;
  int swz = (orig & 7) * 256 + (orig >> 3);
  const int bm = (swz & 15) * 128, bn = (swz >> 4) * 256;

  auto stageA = [&](int buf, int kt) {
    int c = tid;  // 512 chunks of 16B; tile 128 rows x 4 chunks
    int row = c >> 2, ch = c & 3;
    int sch = ch ^ ((row >> 1) & 3);
    GLOAD_LDS16(A + (size_t)(bm + row) * K + kt * BK + sch * 8, Asl + buf * 4096 + c * 8);
  };
  auto stageB = [&](int buf, int kt) {
#pragma unroll
    for (int i = 0; i < 2; ++i) {
      int c = i * 512 + tid;  // 1024 chunks; tile 256 rows x 4 chunks
      int row = c >> 2, ch = c & 3;
      int sch = ch ^ ((row >> 1) & 3);
      GLOAD_LDS16(W + (size_t)(bn + row) * K + kt * BK + sch * 8, Bsl + buf * 8192 + c * 8);
    }
  };

  f32x4 acc[4][4];
#pragma unroll
  for (int i = 0; i < 4; ++i)
#pragma unroll
    for (int j = 0; j < 4; ++j) acc[i][j] = (f32x4){0.f, 0.f, 0.f, 0.f};

  bf16x8 a[4], b[4];

#define FRAG_PH(rl) (((rl) * 64 + l4 * 16) ^ ((((unsigned)(rl) >> 1) & 3) << 4))

  // BODY: compute tile Tt from (a,b); stage Tt+2 into STG; reload a,b with tile Tt+1
  // (from NXT), reads interleaved into the MFMA cluster after each frag's last use.
#define BODY(CUR, NXT, STG, Tt, DO_STAGE, WN)                                             \
  do {                                                                                    \
    if (DO_STAGE) { stageA(STG, (Tt) + 2); stageB(STG, (Tt) + 2); }                       \
    asm volatile("s_waitcnt vmcnt(" #WN ")" ::: "memory");                                \
    __builtin_amdgcn_s_barrier();                                                         \
    {                                                                                     \
      const char* _ab = (const char*)(Asl + (NXT) * 4096);                                \
      const char* _bb = (const char*)(Bsl + (NXT) * 8192);                                \
      __builtin_amdgcn_s_setprio(1);                                                      \
      _Pragma("unroll") for (int mf = 0; mf < 4; ++mf) {                                  \
        _Pragma("unroll") for (int nf = 0; nf < 4; ++nf) {                                \
          acc[mf][nf] =                                                                   \
              __builtin_amdgcn_mfma_f32_16x16x32_bf16(a[mf], b[nf], acc[mf][nf], 0, 0, 0);\
          if (mf == 3) {                                                                  \
            int rl = wn * 64 + nf * 16 + l15;                                             \
            b[nf] = *(const bf16x8*)(_bb + FRAG_PH(rl));                                  \
          }                                                                               \
        }                                                                                 \
        int rl = wm * 64 + mf * 16 + l15;                                                 \
        a[mf] = *(const bf16x8*)(_ab + FRAG_PH(rl));                                      \
      }                                                                                   \
      __builtin_amdgcn_s_setprio(0);                                                      \
    }                                                                                     \
    asm volatile("s_waitcnt lgkmcnt(0)" ::: "memory");                                    \
    __builtin_amdgcn_sched_barrier(0);                                                    \
  } while (0)

  // prologue: stage tiles 0,1 (6 loads); vmcnt(3) -> tile 0 landed; load tile-0 frags
  stageA(0, 0); stageB(0, 0);
  stageA(1, 1); stageB(1, 1);
  asm volatile("s_waitcnt vmcnt(3)" ::: "memory");
  __builtin_amdgcn_s_barrier();
#pragma unroll
  for (int nf = 0; nf < 4; ++nf) {
    int rl = wn * 64 + nf * 16 + l15;
    b[nf] = *(const bf16x8*)((const char*)Bsl + FRAG_PH(rl));
  }
#pragma unroll
  for (int mf = 0; mf < 4; ++mf) {
    int rl = wm * 64 + mf * 16 + l15;
    a[mf] = *(const bf16x8*)((const char*)Asl + FRAG_PH(rl));
  }
  asm volatile("s_waitcnt lgkmcnt(0)" ::: "memory");
  __builtin_amdgcn_sched_barrier(0);

  // bodies 0..29 in triples (buf pattern period 3); last staging body (29) stages tile 31
  for (int T = 0; T < 30; T += 3) {
    BODY(0, 1, 2, T, 1, 3);
    BODY(1, 2, 0, (T + 1), 1, 3);
    BODY(2, 0, 1, (T + 2), 1, 3);
  }
  // body 30: computes tile 30 (buf 0), no stage, drain stage(31); prefetch tile-31 frags
  BODY(0, 1, 2, 30, 0, 0);
  // tail: tile 31, registers only
  __builtin_amdgcn_s_setprio(1);
#pragma unroll
  for (int mf = 0; mf < 4; ++mf)
#pragma unroll
    for (int nf = 0; nf < 4; ++nf)
      acc[mf][nf] = __builtin_amdgcn_mfma_f32_16x16x32_bf16(a[mf], b[nf], acc[mf][nf], 0, 0, 0);
  __builtin_amdgcn_s_setprio(0);
#undef BODY
#undef FRAG_PH

  // ---- fused rule-aggregation epilogue ----
  const int h = bn >> 11;                          // 2048 cols per head
  const int dbase = ((bn & 2047) + wn * 64) >> 5;  // even
#pragma unroll
  for (int mf = 0; mf < 4; ++mf) {
    int gm0 = bm + wm * 64 + mf * 16 + l4 * 4;
    float red[4][2];
#pragma unroll
    for (int q = 0; q < 4; ++q) { red[q][0] = 0.f; red[q][1] = 0.f; }
#pragma unroll
    for (int nf = 0; nf < 4; ++nf) {
      int col = bn + wn * 64 + nf * 16 + l15;
      float bval = bias[col];
      int r = (nf & 1) * 16 + l15;
      int g = nf >> 1;
#pragma unroll
      for (int q = 0; q < 4; ++q) {
        float w = attn[(size_t)(gm0 + q) * 512 + h * 32 + r];
        red[q][g] += (acc[mf][nf][q] + bval) * w;
      }
    }
#pragma unroll
    for (int q = 0; q < 4; ++q)
#pragma unroll
      for (int g = 0; g < 2; ++g) {
        float vv = red[q][g];
        for (int mask = 1; mask < 16; mask <<= 1) vv += __shfl_xor(vv, mask);
        red[q][g] = vv * scale;
      }
    if (l15 == 0) {
#pragma unroll
      for (int q = 0; q < 4; ++q) {
        int m = gm0 + q;
        int bb = m >> 10, s = m & 1023;
        size_t base = (((size_t)(bb * 16 + h)) * 1024 + s) * 64;
        unsigned lo = f32_to_bf16_rne(red[q][0]);
        unsigned hi = f32_to_bf16_rne(red[q][1]);
        ((unsigned*)X)[(base + dbase) >> 1] = lo | (hi << 16);
      }
    }
  }
}

extern "C" void kernel_launch(void* const* d_in, const int* in_sizes, int n_in, void* d_out,
                              int out_size, void* d_ws, size_t ws_size, hipStream_t stream) {
  const float* query = (const float*)d_in[0];
  const float* value = (const float*)d_in[2];
  const float* rk = (const float*)d_in[3];
  const float* rw = (const float*)d_in[4];
  const float* Wq = (const float*)d_in[5];
  const float* bq = (const float*)d_in[6];
  const float* Wv = (const float*)d_in[7];
  const float* bv = (const float*)d_in[8];
  const float* Wo = (const float*)d_in[9];
  const float* bo = (const float*)d_in[10];
  float* out = (float*)d_out;

  const float scale = 0.125f;

  char* p = (char*)d_ws;
  unsigned short* Wv_b = (unsigned short*)p; p += (size_t)33554432 * 2;
  unsigned short* Aq_b = (unsigned short*)p; p += (size_t)2097152 * 2;
  unsigned short* Av_b = (unsigned short*)p; p += (size_t)2097152 * 2;
  unsigned short* Wq_b = (unsigned short*)p; p += (size_t)1048576 * 2;
  unsigned short* Wo_b = (unsigned short*)p; p += (size_t)1048576 * 2;
  float* qf = (float*)p;   p += (size_t)2097152 * 4;
  float* attn = (float*)p; p += (size_t)1048576 * 4;
  unsigned short* X = (unsigned short*)p;

  cvt_all<<<19456, 256, 0, stream>>>(Wv, query, value, Wq, Wo, Wv_b, Aq_b, Av_b, Wq_b, Wo_b);

  // GEMM1: qf = (query @ Wq^T + bq) * scale   (2048 x 1024), 512 blocks
  gemm_bt64<<<dim3(16, 32), 256, 0, stream>>>(Aq_b, Wq_b, bq, scale, 2048, 1024, 1024, qf);
  // fuzzy membership + softmax
  fuzzy2_k<<<dim3(16, 16), 256, 0, stream>>>(qf, rk, rw, attn);
  // GEMM2 fused (128x256, 3-buf, 72KB dynamic LDS, 2 blocks/CU)
  hipFuncSetAttribute((const void*)gemm2_k, hipFuncAttributeMaxDynamicSharedMemorySize, 73728);
  gemm2_k<<<2048, 512, 73728, stream>>>(Av_b, Wv_b, bv, scale, attn, X);
  // GEMM3: out = X @ Wo^T + bo
  gemm_bt64<<<dim3(16, 32), 256, 0, stream>>>(X, Wo_b, bo, 1.0f, 2048, 1024, 1024, out);
}

// Round 8
// 231.966 us; speedup vs baseline: 13.4683x; 1.0138x over previous
//
#include <hip/hip_runtime.h>
#include <hip/hip_bf16.h>
#include <cstdint>

typedef float f32x4 __attribute__((ext_vector_type(4)));
typedef short bf16x8 __attribute__((ext_vector_type(8)));

__device__ __forceinline__ unsigned short f32_to_bf16_rne(float f) {
  unsigned int u = __float_as_uint(f);
  return (unsigned short)((u + 0x7FFFu + ((u >> 16) & 1u)) >> 16);
}

#define GLOAD_LDS16(gptr, lptr)                                                             \
  __builtin_amdgcn_global_load_lds((const __attribute__((address_space(1))) unsigned int*)(gptr), \
                                   (__attribute__((address_space(3))) unsigned int*)(lptr), 16, 0, 0)

// ---------------- fused f32 -> bf16 for all 5 operands (8 elems / thread) ----------------
__global__ __launch_bounds__(256) void cvt_all(const float* __restrict__ wv,
                                               const float* __restrict__ q,
                                               const float* __restrict__ v,
                                               const float* __restrict__ wq,
                                               const float* __restrict__ wo,
                                               unsigned short* __restrict__ wvb,
                                               unsigned short* __restrict__ qb,
                                               unsigned short* __restrict__ vb,
                                               unsigned short* __restrict__ wqb,
                                               unsigned short* __restrict__ wob) {
  int i = blockIdx.x * 256 + threadIdx.x;  // chunk of 8 floats
  const float* src;
  unsigned short* dst;
  int off;
  if (i < 4194304)      { src = wv; dst = wvb; off = i; }
  else if (i < 4456448) { src = q;  dst = qb;  off = i - 4194304; }
  else if (i < 4718592) { src = v;  dst = vb;  off = i - 4456448; }
  else if (i < 4849664) { src = wq; dst = wqb; off = i - 4718592; }
  else                  { src = wo; dst = wob; off = i - 4849664; }
  const float4* s = (const float4*)src;
  float4 a = s[2 * off], b = s[2 * off + 1];
  uint4 o;
  o.x = (unsigned)f32_to_bf16_rne(a.x) | ((unsigned)f32_to_bf16_rne(a.y) << 16);
  o.y = (unsigned)f32_to_bf16_rne(a.z) | ((unsigned)f32_to_bf16_rne(a.w) << 16);
  o.z = (unsigned)f32_to_bf16_rne(b.x) | ((unsigned)f32_to_bf16_rne(b.y) << 16);
  o.w = (unsigned)f32_to_bf16_rne(b.z) | ((unsigned)f32_to_bf16_rne(b.w) << 16);
  ((uint4*)dst)[off] = o;
}

// ---------------- fuzzy membership + softmax: LDS-staged rules, one head per block --------
__global__ __launch_bounds__(256) void fuzzy2_k(const float* __restrict__ qf,
                                                const float* __restrict__ rk,
                                                const float* __restrict__ rw,
                                                float* __restrict__ attn) {
  __shared__ float lk[32][65];
  __shared__ float lc[32][65];
  const int tid = threadIdx.x;
  const int h = blockIdx.y;
  const int mbase = blockIdx.x * 128;

  for (int idx = tid; idx < 2048; idx += 256) {
    int r = idx >> 6, d = idx & 63;
    lk[r][d] = rk[(size_t)(h * 32 + r) * 64 + d];
    float w = rw[(size_t)(h * 32 + r) * 64 + d];
    lc[r][d] = 0.0078125f / (w * w);
  }
  __syncthreads();

  const int g = tid >> 5;
  const int r = tid & 31;
#pragma unroll 1
  for (int it = 0; it < 16; ++it) {
    int m = mbase + it * 8 + g;
    const float* qrow = qf + (size_t)m * 1024 + h * 64;
    float acc = 0.f;
#pragma unroll
    for (int d0 = 0; d0 < 64; d0 += 4) {
      float4 q4 = *(const float4*)(qrow + d0);
      const float* qp = (const float*)&q4;
#pragma unroll
      for (int j = 0; j < 4; ++j) {
        float diff = qp[j] - lk[r][d0 + j];
        acc += lc[r][d0 + j] * diff * diff;
      }
    }
    float z = -acc;
    float mx = z;
#pragma unroll
    for (int mask = 16; mask >= 1; mask >>= 1) mx = fmaxf(mx, __shfl_xor(mx, mask));
    float e = __expf(z - mx);
    float s = e;
#pragma unroll
    for (int mask = 16; mask >= 1; mask >>= 1) s += __shfl_xor(s, mask);
    attn[(size_t)m * 512 + h * 32 + r] = e / s;
  }
}

// ---------------- small bf16 GEMM (64x64 tile, 512 blocks, ~8/CU): C = (A@W^T+b)*scale ----
__global__ __launch_bounds__(256) void gemm_bt64(const unsigned short* __restrict__ A,
                                                 const unsigned short* __restrict__ W,
                                                 const float* __restrict__ bias, float scale,
                                                 int M, int N, int K, float* __restrict__ Cf) {
  constexpr int BK = 32;
  __shared__ unsigned short As[2][64 * BK];
  __shared__ unsigned short Bs[2][64 * BK];
  const int tid = threadIdx.x;
  const int wid = tid >> 6;
  const int lane = tid & 63;
  const int l15 = lane & 15;
  const int l4 = lane >> 4;
  const int bm = blockIdx.y * 64;
  const int bn = blockIdx.x * 64;
  const int wr = (wid >> 1) * 32;
  const int wc = (wid & 1) * 32;

  f32x4 acc[2][2];
#pragma unroll
  for (int i = 0; i < 2; ++i)
#pragma unroll
    for (int j = 0; j < 2; ++j) acc[i][j] = (f32x4){0.f, 0.f, 0.f, 0.f};

  const int nk = K / BK;
  auto stage = [&](int buf, int kt) {
    int c = tid;  // 256 chunks of 16B per 4KB tile
    int row = c >> 2, ch = c & 3;
    int sch = ch ^ ((row >> 1) & 3);
    GLOAD_LDS16(A + (size_t)(bm + row) * K + kt * BK + sch * 8, &As[buf][c * 8]);
    GLOAD_LDS16(W + (size_t)(bn + row) * K + kt * BK + sch * 8, &Bs[buf][c * 8]);
  };

  stage(0, 0);
  __syncthreads();

  for (int kt = 0; kt < nk; ++kt) {
    const int cur = kt & 1;
    if (kt + 1 < nk) stage(cur ^ 1, kt + 1);
    bf16x8 a[2], b[2];
#pragma unroll
    for (int mi = 0; mi < 2; ++mi) {
      int rl = wr + mi * 16 + l15;
      int ph = (rl * 64 + l4 * 16) ^ ((((unsigned)rl >> 1) & 3) << 4);
      a[mi] = *(const bf16x8*)((const char*)&As[cur][0] + ph);
    }
#pragma unroll
    for (int ni = 0; ni < 2; ++ni) {
      int rl = wc + ni * 16 + l15;
      int ph = (rl * 64 + l4 * 16) ^ ((((unsigned)rl >> 1) & 3) << 4);
      b[ni] = *(const bf16x8*)((const char*)&Bs[cur][0] + ph);
    }
#pragma unroll
    for (int mi = 0; mi < 2; ++mi)
#pragma unroll
      for (int ni = 0; ni < 2; ++ni)
        acc[mi][ni] = __builtin_amdgcn_mfma_f32_16x16x32_bf16(a[mi], b[ni], acc[mi][ni], 0, 0, 0);
    __syncthreads();
  }

#pragma unroll
  for (int mi = 0; mi < 2; ++mi) {
#pragma unroll
    for (int ni = 0; ni < 2; ++ni) {
      int gm = bm + wr + mi * 16 + l4 * 4;
      int gn = bn + wc + ni * 16 + l15;
      float bval = bias[gn];
#pragma unroll
      for (int q = 0; q < 4; ++q)
        Cf[(size_t)(gm + q) * N + gn] = (acc[mi][ni][q] + bval) * scale;
    }
  }
}

// ---------------- GEMM2: 256x256 tile, BK=32, 4-buf, dbl-buffered frags, fused agg --------
// A: value bf16 (2048 x 1024), W: Wv bf16 (32768 x 1024)
// X[b,h,s,d] = scale * sum_r attn[m,h,r] * (A[m,:]@W[h*2048+d*32+r,:] + bias)
// vmcnt: 4 gload_lds per tile-stage (2A+2B). BODY(T) issues stage(T+2): queue =
// stage(T+1)[4] + stage(T+2)[4] -> vmcnt(4) waits exactly tile T+1. Both a and b frags
// are register-double-buffered so all 12 ds_reads are WAR-free and spread over MFMA
// groups 0..5; groups 6..7 (8 MFMA ~155cy) cover the tail latency -> lgkmcnt(0) is free.
__global__ __launch_bounds__(512) void gemm2_k(const unsigned short* __restrict__ A,
                                               const unsigned short* __restrict__ W,
                                               const float* __restrict__ bias, float scale,
                                               const float* __restrict__ attn,
                                               unsigned short* __restrict__ X) {
  constexpr int K = 1024, BK = 32, NK = K / BK;  // 32 K-tiles
  extern __shared__ unsigned short lds[];  // A: 4 x 8192, B: 4 x 8192 ushorts = 128 KB
  unsigned short* Asl = lds;
  unsigned short* Bsl = lds + 4 * 8192;
  const int tid = threadIdx.x;
  const int wid = tid >> 6, lane = tid & 63;
  const int l15 = lane & 15, l4 = lane >> 4;
  const int wm = wid >> 2, wn = wid & 3;  // wave tile 128x64

  // XCD-aware bijective swizzle: contiguous col-tile strip per XCD (B-panel L2 reuse)
  int orig = blockIdx.x;
  int swz = (orig & 7) * 128 + (orig >> 3);
  const int bm = (swz & 7) * 256, bn = (swz >> 3) * 256;

  auto stageA = [&](int buf, int kt) {
#pragma unroll
    for (int i = 0; i < 2; ++i) {
      int c = i * 512 + tid;  // 1024 chunks of 16B; tile = 256 rows x 4 chunks
      int row = c >> 2, ch = c & 3;
      int sch = ch ^ ((row >> 1) & 3);  // inverse swizzle on SOURCE (rule #21)
      GLOAD_LDS16(A + (size_t)(bm + row) * K + kt * BK + sch * 8, Asl + buf * 8192 + c * 8);
    }
  };
  auto stageB = [&](int buf, int kt) {
#pragma unroll
    for (int i = 0; i < 2; ++i) {
      int c = i * 512 + tid;
      int row = c >> 2, ch = c & 3;
      int sch = ch ^ ((row >> 1) & 3);
      GLOAD_LDS16(W + (size_t)(bn + row) * K + kt * BK + sch * 8, Bsl + buf * 8192 + c * 8);
    }
  };

  f32x4 acc[8][4];
#pragma unroll
  for (int i = 0; i < 8; ++i)
#pragma unroll
    for (int j = 0; j < 4; ++j) acc[i][j] = (f32x4){0.f, 0.f, 0.f, 0.f};

  bf16x8 a0[8], a1[8], b0[4], b1[4];

#define FRAG_PH(rl) (((rl) * 64 + l4 * 16) ^ ((((unsigned)(rl) >> 1) & 3) << 4))

  // BODY: compute tile Tt from (aC,bC); stage Tt+2; load tile Tt+1 frags into (aN,bN),
  // 12 reads distributed 2-per-group over MFMA groups 0..5.
#define BODY(aC, aN, bC, bN, Tt, DO_STAGE, WN)                                            \
  do {                                                                                    \
    if (DO_STAGE) { stageA(((Tt) + 2) & 3, (Tt) + 2); stageB(((Tt) + 2) & 3, (Tt) + 2); } \
    asm volatile("s_waitcnt vmcnt(" #WN ")" ::: "memory");                                \
    __builtin_amdgcn_s_barrier();                                                         \
    {                                                                                     \
      const char* _ab = (const char*)(Asl + (((Tt) + 1) & 3) * 8192);                     \
      const char* _bb = (const char*)(Bsl + (((Tt) + 1) & 3) * 8192);                     \
      __builtin_amdgcn_s_setprio(1);                                                      \
      _Pragma("unroll") for (int mf = 0; mf < 8; ++mf) {                                  \
        _Pragma("unroll") for (int nf = 0; nf < 4; ++nf)                                  \
          acc[mf][nf] =                                                                   \
              __builtin_amdgcn_mfma_f32_16x16x32_bf16(aC[mf], bC[nf], acc[mf][nf], 0, 0, 0); \
        if (mf < 4) {                                                                     \
          aN[mf] = *(const bf16x8*)(_ab + FRAG_PH(wm * 128 + mf * 16 + l15));             \
          bN[mf] = *(const bf16x8*)(_bb + FRAG_PH(wn * 64 + mf * 16 + l15));              \
        } else if (mf < 6) {                                                              \
          int i0 = 2 * mf - 4, i1 = 2 * mf - 3;                                           \
          aN[i0] = *(const bf16x8*)(_ab + FRAG_PH(wm * 128 + i0 * 16 + l15));             \
          aN[i1] = *(const bf16x8*)(_ab + FRAG_PH(wm * 128 + i1 * 16 + l15));             \
        }                                                                                 \
      }                                                                                   \
      __builtin_amdgcn_s_setprio(0);                                                      \
    }                                                                                     \
    asm volatile("s_waitcnt lgkmcnt(0)" ::: "memory");                                    \
    __builtin_amdgcn_sched_barrier(0);                                                    \
  } while (0)

  // prologue: stage tiles 0,1 (8 loads); vmcnt(4) -> tile 0 landed; load tile-0 frags
  stageA(0, 0); stageB(0, 0);
  stageA(1, 1); stageB(1, 1);
  asm volatile("s_waitcnt vmcnt(4)" ::: "memory");
  __builtin_amdgcn_s_barrier();
#pragma unroll
  for (int nf = 0; nf < 4; ++nf)
    b0[nf] = *(const bf16x8*)((const char*)Bsl + FRAG_PH(wn * 64 + nf * 16 + l15));
#pragma unroll
  for (int mf = 0; mf < 8; ++mf)
    a0[mf] = *(const bf16x8*)((const char*)Asl + FRAG_PH(wm * 128 + mf * 16 + l15));
  asm volatile("s_waitcnt lgkmcnt(0)" ::: "memory");
  __builtin_amdgcn_sched_barrier(0);

  // bodies 0..29 (stage reaches tile 31 at body 29)
  for (int T = 0; T < 30; T += 2) {
    BODY(a0, a1, b0, b1, T, 1, 4);
    BODY(a1, a0, b1, b0, (T + 1), 1, 4);
  }
  // body 30: no stage; drain stage(31); load tile-31 frags into (a1,b1)
  BODY(a0, a1, b0, b1, 30, 0, 0);
  // tail: tile 31, registers only
  __builtin_amdgcn_s_setprio(1);
#pragma unroll
  for (int mf = 0; mf < 8; ++mf)
#pragma unroll
    for (int nf = 0; nf < 4; ++nf)
      acc[mf][nf] = __builtin_amdgcn_mfma_f32_16x16x32_bf16(a1[mf], b1[nf], acc[mf][nf], 0, 0, 0);
  __builtin_amdgcn_s_setprio(0);
#undef BODY
#undef FRAG_PH

  // ---- fused rule-aggregation epilogue (per-mf to bound register pressure) ----
  const int h = bn >> 11;                          // 2048 cols per head
  const int dbase = ((bn & 2047) + wn * 64) >> 5;  // even
#pragma unroll
  for (int mf = 0; mf < 8; ++mf) {
    int gm0 = bm + wm * 128 + mf * 16 + l4 * 4;
    float red[4][2];
#pragma unroll
    for (int q = 0; q < 4; ++q) { red[q][0] = 0.f; red[q][1] = 0.f; }
#pragma unroll
    for (int nf = 0; nf < 4; ++nf) {
      int col = bn + wn * 64 + nf * 16 + l15;
      float bval = bias[col];
      int r = (nf & 1) * 16 + l15;
      int g = nf >> 1;
#pragma unroll
      for (int q = 0; q < 4; ++q) {
        float w = attn[(size_t)(gm0 + q) * 512 + h * 32 + r];
        red[q][g] += (acc[mf][nf][q] + bval) * w;
      }
    }
#pragma unroll
    for (int q = 0; q < 4; ++q)
#pragma unroll
      for (int g = 0; g < 2; ++g) {
        float vv = red[q][g];
        for (int mask = 1; mask < 16; mask <<= 1) vv += __shfl_xor(vv, mask);
        red[q][g] = vv * scale;
      }
    if (l15 == 0) {
#pragma unroll
      for (int q = 0; q < 4; ++q) {
        int m = gm0 + q;
        int bb = m >> 10, s = m & 1023;
        size_t base = (((size_t)(bb * 16 + h)) * 1024 + s) * 64;
        unsigned lo = f32_to_bf16_rne(red[q][0]);
        unsigned hi = f32_to_bf16_rne(red[q][1]);
        ((unsigned*)X)[(base + dbase) >> 1] = lo | (hi << 16);
      }
    }
  }
}

extern "C" void kernel_launch(void* const* d_in, const int* in_sizes, int n_in, void* d_out,
                              int out_size, void* d_ws, size_t ws_size, hipStream_t stream) {
  const float* query = (const float*)d_in[0];
  const float* value = (const float*)d_in[2];
  const float* rk = (const float*)d_in[3];
  const float* rw = (const float*)d_in[4];
  const float* Wq = (const float*)d_in[5];
  const float* bq = (const float*)d_in[6];
  const float* Wv = (const float*)d_in[7];
  const float* bv = (const float*)d_in[8];
  const float* Wo = (const float*)d_in[9];
  const float* bo = (const float*)d_in[10];
  float* out = (float*)d_out;

  const float scale = 0.125f;

  char* p = (char*)d_ws;
  unsigned short* Wv_b = (unsigned short*)p; p += (size_t)33554432 * 2;
  unsigned short* Aq_b = (unsigned short*)p; p += (size_t)2097152 * 2;
  unsigned short* Av_b = (unsigned short*)p; p += (size_t)2097152 * 2;
  unsigned short* Wq_b = (unsigned short*)p; p += (size_t)1048576 * 2;
  unsigned short* Wo_b = (unsigned short*)p; p += (size_t)1048576 * 2;
  float* qf = (float*)p;   p += (size_t)2097152 * 4;
  float* attn = (float*)p; p += (size_t)1048576 * 4;
  unsigned short* X = (unsigned short*)p;

  cvt_all<<<19456, 256, 0, stream>>>(Wv, query, value, Wq, Wo, Wv_b, Aq_b, Av_b, Wq_b, Wo_b);

  // GEMM1: qf = (query @ Wq^T + bq) * scale   (2048 x 1024), 512 blocks
  gemm_bt64<<<dim3(16, 32), 256, 0, stream>>>(Aq_b, Wq_b, bq, scale, 2048, 1024, 1024, qf);
  // fuzzy membership + softmax
  fuzzy2_k<<<dim3(16, 16), 256, 0, stream>>>(qf, rk, rw, attn);
  // GEMM2 fused (256^2, 4-buf, 128KB dynamic LDS, double-buffered fragments)
  hipFuncSetAttribute((const void*)gemm2_k, hipFuncAttributeMaxDynamicSharedMemorySize, 131072);
  gemm2_k<<<1024, 512, 131072, stream>>>(Av_b, Wv_b, bv, scale, attn, X);
  // GEMM3: out = X @ Wo^T + bo
  gemm_bt64<<<dim3(16, 32), 256, 0, stream>>>(X, Wo_b, bo, 1.0f, 2048, 1024, 1024, out);
}